// Round 2
// baseline (475.276 us; speedup 1.0000x reference)
//
#include <hip/hip_runtime.h>

// QuantFinanceAttention: B=2, T=2048, C=1024, H=16, dk=64.
// ALL float inputs/outputs are fp32 (reference is jnp.float32; threshold = 2% of max|ref|).
// Internally: convert to bf16 at LDS-staging time, bf16 MFMA, fp32 accumulate.
// d_in: 0=x[B,T,C] 1=Wq 2=Wk 3=Wv 4=Wo (all [C,C]) 5=bo[C] 6=sector_bias[16]
//       7=sector_weights[B,T] 8=mask (tril int32, ignored - causal computed analytically)
// ws: q,k,v in [B,H,T,dk] bf16 (8.39MB each), attn_out [B,T,C] bf16 (8.39MB) = 33.6MB

typedef __bf16 bf16x8 __attribute__((ext_vector_type(8)));
typedef float f32x4 __attribute__((ext_vector_type(4)));
typedef unsigned short u16x8 __attribute__((ext_vector_type(8)));

__device__ __forceinline__ float bf2f(unsigned short s) {
    union { unsigned int u; float f; } c; c.u = ((unsigned int)s) << 16; return c.f;
}
__device__ __forceinline__ unsigned short f2bf(float f) {
    union { float f; unsigned int u; } c; c.f = f;
    unsigned int u = c.u;
    unsigned int r = u + 0x7fffu + ((u >> 16) & 1u);  // RNE
    return (unsigned short)(r >> 16);
}
// Load 8 fp32, convert RNE->bf16, store 16B to LDS.
__device__ __forceinline__ void stage8_f32(unsigned short* dst, const float* src) {
    const float4 a = *(const float4*)src;
    const float4 b = *(const float4*)(src + 4);
    u16x8 v;
    v[0] = f2bf(a.x); v[1] = f2bf(a.y); v[2] = f2bf(a.z); v[3] = f2bf(a.w);
    v[4] = f2bf(b.x); v[5] = f2bf(b.y); v[6] = f2bf(b.z); v[7] = f2bf(b.w);
    *(u16x8*)dst = v;
}

// C[m,n] = sum_k A[m,k]*W[n,k]  (A:[4096,1024], W:[1024,1024] fp32 row-major)
// MODE 0: A fp32;  out = bf16 ws, scattered to [B,H,T,dk] head-major
// MODE 1: A bf16 (ws); out = fp32 d_out[m*1024+n] + bias[n]
template<int MODE>
__global__ __launch_bounds__(256) void gemm_bt(
    const void* __restrict__ Av, const float* __restrict__ W,
    void* __restrict__ outv, const float* __restrict__ bias)
{
    constexpr int K = 1024, BK = 32;
    __shared__ __align__(16) unsigned short As[128 * BK];
    __shared__ __align__(16) unsigned short Bs[128 * BK];
    const int tid = threadIdx.x;
    const int wid = tid >> 6, lane = tid & 63, g = lane >> 4, l = lane & 15;
    const int wm = (wid & 1) * 64, wn = (wid >> 1) * 64;
    const int m0 = blockIdx.y * 128, n0 = blockIdx.x * 128;

    f32x4 acc[4][4];
#pragma unroll
    for (int i = 0; i < 4; ++i)
#pragma unroll
        for (int j = 0; j < 4; ++j) acc[i][j] = f32x4{0.f, 0.f, 0.f, 0.f};

    for (int k0 = 0; k0 < K; k0 += BK) {
        __syncthreads();
#pragma unroll
        for (int s = 0; s < 2; ++s) {
            const int idx = tid + s * 256;       // 0..511: 128 rows x 4 col-groups of 8
            const int r = idx >> 2;
            const int c = (idx & 3) * 8;
            if (MODE == 0) {
                stage8_f32(&As[r * BK + c], (const float*)Av + (size_t)(m0 + r) * K + k0 + c);
            } else {
                *(u16x8*)&As[r * BK + c] =
                    *(const u16x8*)((const unsigned short*)Av + (size_t)(m0 + r) * K + k0 + c);
            }
            stage8_f32(&Bs[r * BK + c], W + (size_t)(n0 + r) * K + k0 + c);
        }
        __syncthreads();
        bf16x8 af[4], bfr[4];
#pragma unroll
        for (int im = 0; im < 4; ++im) af[im]  = *(const bf16x8*)&As[(wm + im * 16 + l) * BK + g * 8];
#pragma unroll
        for (int in = 0; in < 4; ++in) bfr[in] = *(const bf16x8*)&Bs[(wn + in * 16 + l) * BK + g * 8];
#pragma unroll
        for (int im = 0; im < 4; ++im)
#pragma unroll
            for (int in = 0; in < 4; ++in)
                acc[im][in] = __builtin_amdgcn_mfma_f32_16x16x32_bf16(af[im], bfr[in], acc[im][in], 0, 0, 0);
    }

#pragma unroll
    for (int im = 0; im < 4; ++im) {
#pragma unroll
        for (int in = 0; in < 4; ++in) {
            const int mbase = m0 + wm + im * 16 + g * 4;
            const int n = n0 + wn + in * 16 + l;
#pragma unroll
            for (int i = 0; i < 4; ++i) {
                const int m = mbase + i;
                const float v = acc[im][in][i];
                if (MODE == 0) {
                    const int b = m >> 11, t = m & 2047, h = n >> 6, d = n & 63;
                    ((unsigned short*)outv)[((((size_t)b * 16 + h) * 2048 + t) << 6) + d] = f2bf(v);
                } else {
                    ((float*)outv)[(size_t)m * 1024 + n] = v + bias[n];
                }
            }
        }
    }
}

// In-place RoPE on q and k ([B,H,T,64] bf16 each). One thread per (tensor, bh, t, d<32).
__global__ __launch_bounds__(256) void rope_kernel(unsigned short* __restrict__ q,
                                                   unsigned short* __restrict__ k)
{
    const int idx = blockIdx.x * 256 + threadIdx.x;  // [0, 2*2097152)
    const int PER = 2 * 16 * 2048 * 32;
    unsigned short* buf = (idx < PER) ? q : k;
    const int id = (idx < PER) ? idx : idx - PER;
    const int d = id & 31;
    const int t = (id >> 5) & 2047;
    const int bh = id >> 16;
    const size_t base = ((size_t)bh * 2048 + t) * 64;
    const float inv = powf(10000.0f, -(float)d * (1.0f / 32.0f));
    const float ang = (float)t * inv;
    const float c = cosf(ang), s = sinf(ang);
    const float x1 = bf2f(buf[base + d]);
    const float x2 = bf2f(buf[base + d + 32]);
    buf[base + d]      = f2bf(x1 * c - x2 * s);
    buf[base + d + 32] = f2bf(x2 * c + x1 * s);
}

// Flash attention: block = (q-tile of 64 rows, bh). 4 waves x 16 q-rows.
// K/V chunks of 32 keys staged in LDS; online softmax; P via per-wave LDS round-trip.
__global__ __launch_bounds__(256) void flash_attn(
    const unsigned short* __restrict__ Q, const unsigned short* __restrict__ Kg,
    const unsigned short* __restrict__ Vg, const float* __restrict__ sbias,
    const float* __restrict__ sw, unsigned short* __restrict__ attn)
{
    constexpr int T = 2048;
    __shared__ __align__(16) unsigned short Ks[32 * 72];
    __shared__ __align__(16) unsigned short Vs[32 * 68];
    __shared__ __align__(16) unsigned short Ps[4][16 * 40];
    const int tid = threadIdx.x, wid = tid >> 6, lane = tid & 63, g = lane >> 4, l = lane & 15;
    const int q0 = blockIdx.x * 64, bh = blockIdx.y, b = bh >> 4, h = bh & 15;
    const size_t base = (size_t)bh * T * 64;
    const float bias = sbias[h];
    const float* swb = sw + b * T;

    const int qrow_f = q0 + wid * 16 + l;                  // A-operand row
    const bf16x8 qf0 = *(const bf16x8*)&Q[base + (size_t)qrow_f * 64 + g * 8];
    const bf16x8 qf1 = *(const bf16x8*)&Q[base + (size_t)qrow_f * 64 + 32 + g * 8];

    float mrow[4] = {-1e30f, -1e30f, -1e30f, -1e30f};
    float lrow[4] = {0.f, 0.f, 0.f, 0.f};
    f32x4 oacc[4];
#pragma unroll
    for (int dt = 0; dt < 4; ++dt) oacc[dt] = f32x4{0.f, 0.f, 0.f, 0.f};

    const int nchunk = (q0 + 64) >> 5;
    for (int ch = 0; ch < nchunk; ++ch) {
        const int k0 = ch * 32;
        __syncthreads();
        {   // stage K: 32x64 bf16, one 16B vector per thread
            const int r = tid >> 3, c = (tid & 7) * 8;
            *(bf16x8*)&Ks[r * 72 + c] = *(const bf16x8*)&Kg[base + (size_t)(k0 + r) * 64 + c];
        }
#pragma unroll
        for (int s = 0; s < 2; ++s) {  // stage V: 32x64, two 8B vectors per thread
            const int idx = tid + s * 256;
            const int r = idx >> 4, c = (idx & 15) * 4;
            *(unsigned long long*)&Vs[r * 68 + c] =
                *(const unsigned long long*)&Vg[base + (size_t)(k0 + r) * 64 + c];
        }
        __syncthreads();

        // S = Q K^T for two 16-key subtiles (C-layout: row=g*4+i, col=l)
        float sv[2][4];
#pragma unroll
        for (int sub = 0; sub < 2; ++sub) {
            const bf16x8 kf0 = *(const bf16x8*)&Ks[(sub * 16 + l) * 72 + g * 8];
            const bf16x8 kf1 = *(const bf16x8*)&Ks[(sub * 16 + l) * 72 + 32 + g * 8];
            f32x4 s = f32x4{0.f, 0.f, 0.f, 0.f};
            s = __builtin_amdgcn_mfma_f32_16x16x32_bf16(qf0, kf0, s, 0, 0, 0);
            s = __builtin_amdgcn_mfma_f32_16x16x32_bf16(qf1, kf1, s, 0, 0, 0);
            const int kc = k0 + sub * 16 + l;
            const float w = swb[kc];
#pragma unroll
            for (int i = 0; i < 4; ++i) {
                const int qr = q0 + wid * 16 + g * 4 + i;
                const float x = (s[i] * 0.125f + bias) * w;  // (scores*SCALE + bias) * weight
                sv[sub][i] = (kc <= qr) ? x : -1e30f;        // causal mask
            }
        }

        // online softmax per q-row (reduce across the 16 lanes of this row-group)
        float alpha[4];
#pragma unroll
        for (int i = 0; i < 4; ++i) {
            float mx = fmaxf(sv[0][i], sv[1][i]);
#pragma unroll
            for (int off = 1; off < 16; off <<= 1) mx = fmaxf(mx, __shfl_xor(mx, off));
            const float mnew = fmaxf(mrow[i], mx);
            alpha[i] = __expf(mrow[i] - mnew);
            mrow[i] = mnew;
            const float p0 = __expf(sv[0][i] - mnew);
            const float p1 = __expf(sv[1][i] - mnew);
            sv[0][i] = p0; sv[1][i] = p1;
            float rs = p0 + p1;
#pragma unroll
            for (int off = 1; off < 16; off <<= 1) rs += __shfl_xor(rs, off);
            lrow[i] = lrow[i] * alpha[i] + rs;
        }
#pragma unroll
        for (int dt = 0; dt < 4; ++dt)
#pragma unroll
            for (int i = 0; i < 4; ++i) oacc[dt][i] *= alpha[i];

        // P: C-layout -> LDS -> A-layout (per-wave buffer; same-wave DS ops are in-order)
#pragma unroll
        for (int sub = 0; sub < 2; ++sub)
#pragma unroll
            for (int i = 0; i < 4; ++i)
                Ps[wid][(g * 4 + i) * 40 + sub * 16 + l] = f2bf(sv[sub][i]);
        __threadfence_block();
        const bf16x8 pf = *(const bf16x8*)&Ps[wid][l * 40 + g * 8];  // A: [q=l][key=g*8+j]

        // O += P V  (B-operand: [n=d][k=key] = V^T, scalar LDS gathers)
#pragma unroll
        for (int dt = 0; dt < 4; ++dt) {
            bf16x8 vf;
#pragma unroll
            for (int j = 0; j < 8; ++j) {
                union { unsigned short s; __bf16 bv; } c;
                c.s = Vs[(g * 8 + j) * 68 + dt * 16 + l];
                vf[j] = c.bv;
            }
            oacc[dt] = __builtin_amdgcn_mfma_f32_16x16x32_bf16(pf, vf, oacc[dt], 0, 0, 0);
        }
    }

#pragma unroll
    for (int i = 0; i < 4; ++i) lrow[i] = 1.0f / lrow[i];
#pragma unroll
    for (int dt = 0; dt < 4; ++dt) {
#pragma unroll
        for (int i = 0; i < 4; ++i) {
            const int qr = q0 + wid * 16 + g * 4 + i;
            const int d = dt * 16 + l;
            attn[(size_t)(b * T + qr) * 1024 + h * 64 + d] = f2bf(oacc[dt][i] * lrow[i]);
        }
    }
}

extern "C" void kernel_launch(void* const* d_in, const int* in_sizes, int n_in,
                              void* d_out, int out_size, void* d_ws, size_t ws_size,
                              hipStream_t stream) {
    const float* x  = (const float*)d_in[0];
    const float* Wq = (const float*)d_in[1];
    const float* Wk = (const float*)d_in[2];
    const float* Wv = (const float*)d_in[3];
    const float* Wo = (const float*)d_in[4];
    const float* bo = (const float*)d_in[5];
    const float* sb = (const float*)d_in[6];
    const float* sw = (const float*)d_in[7];
    // d_in[8] = mask: strict causal tril (int32), computed analytically in-kernel.

    unsigned short* q    = (unsigned short*)d_ws;
    unsigned short* k    = q + 4194304;   // 2*16*2048*64 bf16
    unsigned short* v    = k + 4194304;
    unsigned short* attn = v + 4194304;
    float* out = (float*)d_out;

    const dim3 gblk(256), ggrid(8, 32);   // N/128 x M/128
    gemm_bt<0><<<ggrid, gblk, 0, stream>>>(x, Wq, q, nullptr);
    gemm_bt<0><<<ggrid, gblk, 0, stream>>>(x, Wk, k, nullptr);
    gemm_bt<0><<<ggrid, gblk, 0, stream>>>(x, Wv, v, nullptr);
    rope_kernel<<<16384, 256, 0, stream>>>(q, k);
    flash_attn<<<dim3(32, 32), 256, 0, stream>>>(q, k, v, sb, sw, attn);
    gemm_bt<1><<<ggrid, gblk, 0, stream>>>(attn, Wo, out, bo);
}

// Round 3
// 274.010 us; speedup vs baseline: 1.7345x; 1.7345x over previous
//
#include <hip/hip_runtime.h>

// QuantFinanceAttention: B=2, T=2048, C=1024, H=16, dk=64. fp32 I/O, bf16 MFMA internals.
// Pipeline: cvt W->bf16 | QKV gemm (m97-style, rope fused in epilogue) | flash (paired
// q-tiles, 64-key chunks) | cvt Wo | proj gemm (fp32 out + bias).

typedef __bf16 bf16x8 __attribute__((ext_vector_type(8)));
typedef float f32x4 __attribute__((ext_vector_type(4)));
typedef unsigned short u16x8 __attribute__((ext_vector_type(8)));

__device__ __forceinline__ float bf2f(unsigned short s) {
    union { unsigned int u; float f; } c; c.u = ((unsigned int)s) << 16; return c.f;
}
__device__ __forceinline__ unsigned short f2bf(float f) {
    union { float f; unsigned int u; } c; c.f = f;
    unsigned int u = c.u;
    unsigned int r = u + 0x7fffu + ((u >> 16) & 1u);  // RNE
    return (unsigned short)(r >> 16);
}
__device__ __forceinline__ void stage8_f32(unsigned short* dst, const float* src) {
    const float4 a = *(const float4*)src;
    const float4 b = *(const float4*)(src + 4);
    u16x8 v;
    v[0] = f2bf(a.x); v[1] = f2bf(a.y); v[2] = f2bf(a.z); v[3] = f2bf(a.w);
    v[4] = f2bf(b.x); v[5] = f2bf(b.y); v[6] = f2bf(b.z); v[7] = f2bf(b.w);
    *(u16x8*)dst = v;
}
// async global->LDS, 16B per lane; LDS dest = wave-uniform base + lane*16
__device__ __forceinline__ void async16(const unsigned short* g, unsigned short* l) {
    __builtin_amdgcn_global_load_lds(
        (const __attribute__((address_space(1))) void*)g,
        (__attribute__((address_space(3))) void*)l, 16, 0, 0);
}

__global__ __launch_bounds__(256) void cvt_f32_bf16(const float* __restrict__ in,
                                                    unsigned short* __restrict__ out, int n8)
{
    const int i = blockIdx.x * 256 + threadIdx.x;
    if (i < n8) stage8_f32(&out[(size_t)i * 8], &in[(size_t)i * 8]);
}

// C[m,n] = sum_k A[m,k]*W[n,k], K=1024. W: bf16 (base + z*1M for MODE 0).
// MODE 0: out = qkv bf16 head-major [z][bh][t][d], rope fused for z<2. A: bf16 if A_BF16 else fp32.
// MODE 1: out = fp32 [m][n] + bias[n]. A: bf16.
template<int MODE, int A_BF16>
__global__ __launch_bounds__(256) void gemm_bt(
    const void* __restrict__ Av, const unsigned short* __restrict__ Wb,
    void* __restrict__ outv, const float* __restrict__ bias)
{
    constexpr int K = 1024, BK = 32;
    __shared__ __align__(16) unsigned short As[128 * BK];
    __shared__ __align__(16) unsigned short Bs[128 * BK];
    const int tid = threadIdx.x;
    const int wid = tid >> 6, lane = tid & 63, g = lane >> 4, l = lane & 15;
    const int wm = (wid & 1) * 64, wn = (wid >> 1) * 64;
    const int m0 = blockIdx.y * 128, n0 = blockIdx.x * 128;
    const int z = blockIdx.z;
    const unsigned short* W = Wb + (size_t)z * 1048576;

    f32x4 acc[4][4];
#pragma unroll
    for (int i = 0; i < 4; ++i)
#pragma unroll
        for (int j = 0; j < 4; ++j) acc[i][j] = f32x4{0.f, 0.f, 0.f, 0.f};

    const int r = tid >> 2;            // 0..63
    const int c = (tid & 3) * 8;       // 0,8,16,24
    unsigned short* AsW = &As[wid * 512];   // per-wave base: lane lands at +lane*16B
    unsigned short* BsW = &Bs[wid * 512];

    for (int k0 = 0; k0 < K; k0 += BK) {
        __syncthreads();
        if (A_BF16) {
            const unsigned short* A = (const unsigned short*)Av;
            async16(&A[(size_t)(m0 + r) * K + k0 + c], AsW);
            async16(&A[(size_t)(m0 + 64 + r) * K + k0 + c], AsW + 2048);
        } else {
            const float* A = (const float*)Av;
            stage8_f32(&As[tid * 8],        &A[(size_t)(m0 + r) * K + k0 + c]);
            stage8_f32(&As[tid * 8 + 2048], &A[(size_t)(m0 + 64 + r) * K + k0 + c]);
        }
        async16(&W[(size_t)(n0 + r) * K + k0 + c], BsW);
        async16(&W[(size_t)(n0 + 64 + r) * K + k0 + c], BsW + 2048);
        __syncthreads();

        bf16x8 af[4], bfr[4];
#pragma unroll
        for (int im = 0; im < 4; ++im) af[im]  = *(const bf16x8*)&As[(wm + im * 16 + l) * BK + g * 8];
#pragma unroll
        for (int in = 0; in < 4; ++in) bfr[in] = *(const bf16x8*)&Bs[(wn + in * 16 + l) * BK + g * 8];
#pragma unroll
        for (int im = 0; im < 4; ++im)
#pragma unroll
            for (int in = 0; in < 4; ++in)
                acc[im][in] = __builtin_amdgcn_mfma_f32_16x16x32_bf16(af[im], bfr[in], acc[im][in], 0, 0, 0);
    }

    if (MODE == 1) {
#pragma unroll
        for (int im = 0; im < 4; ++im)
#pragma unroll
            for (int in = 0; in < 4; ++in) {
                const int n = n0 + wn + in * 16 + l;
#pragma unroll
                for (int i = 0; i < 4; ++i) {
                    const int m = m0 + wm + im * 16 + g * 4 + i;
                    ((float*)outv)[(size_t)m * 1024 + n] = acc[im][in][i] + bias[n];
                }
            }
    } else {
        unsigned short* outq = (unsigned short*)outv + (size_t)z * 4194304;
        if (z < 2) {
            // rope: pair (d, d+32) = (acc[.][in], acc[.][in+2]), in in {0,1}; d = in*16+l
            float freq[2];
#pragma unroll
            for (int in = 0; in < 2; ++in)
                freq[in] = exp2f(-(float)(in * 16 + l) * 0.41524101186f);  // log2(10000)/32
#pragma unroll
            for (int im = 0; im < 4; ++im)
#pragma unroll
                for (int i = 0; i < 4; ++i) {
                    const int m = m0 + wm + im * 16 + g * 4 + i;
                    const int b = m >> 11, t = m & 2047;
#pragma unroll
                    for (int in = 0; in < 2; ++in) {
                        const int n = n0 + wn + in * 16 + l;
                        const int h = n >> 6, d = n & 63;  // d in [0,32)
                        const float ang = (float)t * freq[in];
                        const float cs = __cosf(ang), sn = __sinf(ang);
                        const float x1 = acc[im][in][i], x2 = acc[im][in + 2][i];
                        const size_t bidx = (((size_t)b * 16 + h) * 2048 + t) << 6;
                        outq[bidx + d]      = f2bf(x1 * cs - x2 * sn);
                        outq[bidx + d + 32] = f2bf(x2 * cs + x1 * sn);
                    }
                }
        } else {
#pragma unroll
            for (int im = 0; im < 4; ++im)
#pragma unroll
                for (int in = 0; in < 4; ++in) {
                    const int n = n0 + wn + in * 16 + l;
                    const int h = n >> 6, d = n & 63;
#pragma unroll
                    for (int i = 0; i < 4; ++i) {
                        const int m = m0 + wm + im * 16 + g * 4 + i;
                        const int b = m >> 11, t = m & 2047;
                        outq[((((size_t)b * 16 + h) * 2048 + t) << 6) + d] = f2bf(acc[im][in][i]);
                    }
                }
        }
    }
}

// Flash attention, paired q-tiles (p, 31-p) for load balance; 64-key chunks.
__global__ __launch_bounds__(256) void flash_attn(
    const unsigned short* __restrict__ QKV, const float* __restrict__ sbias,
    const float* __restrict__ sw, unsigned short* __restrict__ attn)
{
    constexpr int T = 2048;
    __shared__ __align__(16) unsigned short Ks[64 * 72];
    __shared__ __align__(16) unsigned short Vs[64 * 68];
    __shared__ __align__(16) unsigned short Ps[4][16 * 72];
    const int tid = threadIdx.x, wid = tid >> 6, lane = tid & 63, g = lane >> 4, l = lane & 15;
    const int p = blockIdx.x, bh = blockIdx.y, b = bh >> 4, h = bh & 15;
    const unsigned short* Q  = QKV;
    const unsigned short* Kg = QKV + 4194304;
    const unsigned short* Vg = QKV + 8388608;
    const size_t base = (size_t)bh * T * 64;
    const float bias = sbias[h];
    const float* swb = sw + b * T;

    for (int pass = 0; pass < 2; ++pass) {
        const int qt = pass ? (31 - p) : p;
        const int q0 = qt * 64;
        const int qrow = q0 + wid * 16 + l;
        const bf16x8 qf0 = *(const bf16x8*)&Q[base + (size_t)qrow * 64 + g * 8];
        const bf16x8 qf1 = *(const bf16x8*)&Q[base + (size_t)qrow * 64 + 32 + g * 8];

        float mrow[4] = {-1e30f, -1e30f, -1e30f, -1e30f};
        float lrow[4] = {0.f, 0.f, 0.f, 0.f};
        f32x4 oacc[4];
#pragma unroll
        for (int dt = 0; dt < 4; ++dt) oacc[dt] = f32x4{0.f, 0.f, 0.f, 0.f};

        for (int ch = 0; ch <= qt; ++ch) {
            const int k0 = ch * 64;
            __syncthreads();
            {   // stage K: 64x64 bf16, 2x16B per thread
                const int kr = tid >> 3, kc = (tid & 7) * 8;
                *(u16x8*)&Ks[kr * 72 + kc]        = *(const u16x8*)&Kg[base + (size_t)(k0 + kr) * 64 + kc];
                *(u16x8*)&Ks[(kr + 32) * 72 + kc] = *(const u16x8*)&Kg[base + (size_t)(k0 + 32 + kr) * 64 + kc];
            }
#pragma unroll
            for (int s = 0; s < 4; ++s) {  // stage V: 64x64, 4x8B per thread
                const int idx = tid + s * 256;
                const int vr = idx >> 4, vc = (idx & 15) * 4;
                *(unsigned long long*)&Vs[vr * 68 + vc] =
                    *(const unsigned long long*)&Vg[base + (size_t)(k0 + vr) * 64 + vc];
            }
            __syncthreads();

            const bool diag = (ch == qt);
            float sv[4][4];
#pragma unroll
            for (int sub = 0; sub < 4; ++sub) {
                const bf16x8 kf0 = *(const bf16x8*)&Ks[(sub * 16 + l) * 72 + g * 8];
                const bf16x8 kf1 = *(const bf16x8*)&Ks[(sub * 16 + l) * 72 + 32 + g * 8];
                f32x4 s4 = f32x4{0.f, 0.f, 0.f, 0.f};
                s4 = __builtin_amdgcn_mfma_f32_16x16x32_bf16(qf0, kf0, s4, 0, 0, 0);
                s4 = __builtin_amdgcn_mfma_f32_16x16x32_bf16(qf1, kf1, s4, 0, 0, 0);
                const int kc = k0 + sub * 16 + l;
                const float w = swb[kc];
#pragma unroll
                for (int i = 0; i < 4; ++i) {
                    float x = (s4[i] * 0.125f + bias) * w;
                    if (diag) {
                        const int qr = q0 + wid * 16 + g * 4 + i;
                        x = (kc <= qr) ? x : -1e30f;
                    }
                    sv[sub][i] = x;
                }
            }

            float alpha[4];
#pragma unroll
            for (int i = 0; i < 4; ++i) {
                float mx = fmaxf(fmaxf(sv[0][i], sv[1][i]), fmaxf(sv[2][i], sv[3][i]));
#pragma unroll
                for (int off = 1; off < 16; off <<= 1) mx = fmaxf(mx, __shfl_xor(mx, off));
                const float mnew = fmaxf(mrow[i], mx);
                alpha[i] = __expf(mrow[i] - mnew);
                mrow[i] = mnew;
                float rs = 0.f;
#pragma unroll
                for (int sub = 0; sub < 4; ++sub) {
                    sv[sub][i] = __expf(sv[sub][i] - mnew);
                    rs += sv[sub][i];
                }
#pragma unroll
                for (int off = 1; off < 16; off <<= 1) rs += __shfl_xor(rs, off);
                lrow[i] = lrow[i] * alpha[i] + rs;
            }
#pragma unroll
            for (int dt = 0; dt < 4; ++dt)
#pragma unroll
                for (int i = 0; i < 4; ++i) oacc[dt][i] *= alpha[i];

            // P: C-layout -> LDS -> A-layout (per-wave buffer)
#pragma unroll
            for (int sub = 0; sub < 4; ++sub)
#pragma unroll
                for (int i = 0; i < 4; ++i)
                    Ps[wid][(g * 4 + i) * 72 + sub * 16 + l] = f2bf(sv[sub][i]);
            __threadfence_block();
            bf16x8 pf[2];
            pf[0] = *(const bf16x8*)&Ps[wid][l * 72 + g * 8];
            pf[1] = *(const bf16x8*)&Ps[wid][l * 72 + 32 + g * 8];

#pragma unroll
            for (int ks = 0; ks < 2; ++ks)
#pragma unroll
                for (int dt = 0; dt < 4; ++dt) {
                    bf16x8 vf;
#pragma unroll
                    for (int j = 0; j < 8; ++j) {
                        union { unsigned short s; __bf16 bv; } cu;
                        cu.s = Vs[(ks * 32 + g * 8 + j) * 68 + dt * 16 + l];
                        vf[j] = cu.bv;
                    }
                    oacc[dt] = __builtin_amdgcn_mfma_f32_16x16x32_bf16(pf[ks], vf, oacc[dt], 0, 0, 0);
                }
        }

#pragma unroll
        for (int i = 0; i < 4; ++i) lrow[i] = 1.0f / lrow[i];
#pragma unroll
        for (int dt = 0; dt < 4; ++dt)
#pragma unroll
            for (int i = 0; i < 4; ++i) {
                const int qr = q0 + wid * 16 + g * 4 + i;
                attn[(size_t)(b * T + qr) * 1024 + h * 64 + dt * 16 + l] = f2bf(oacc[dt][i] * lrow[i]);
            }
    }
}

extern "C" void kernel_launch(void* const* d_in, const int* in_sizes, int n_in,
                              void* d_out, int out_size, void* d_ws, size_t ws_size,
                              hipStream_t stream) {
    const float* x  = (const float*)d_in[0];
    const float* Wq = (const float*)d_in[1];
    const float* Wk = (const float*)d_in[2];
    const float* Wv = (const float*)d_in[3];
    const float* Wo = (const float*)d_in[4];
    const float* bo = (const float*)d_in[5];
    const float* sb = (const float*)d_in[6];
    const float* sw = (const float*)d_in[7];

    const size_t QKV_SZ = 4194304;   // shorts per q/k/v tensor
    const size_t W_SZ   = 1048576;   // shorts per weight matrix
    unsigned short* ws16 = (unsigned short*)d_ws;
    const bool big = ws_size >= 2 * (4 * QKV_SZ + 4 * W_SZ);  // 41.9 MB

    unsigned short *qkv, *attnb, *Wb3, *Wob, *xb = nullptr;
    if (big) {
        xb    = ws16;                 // x bf16 [4096,1024]
        Wb3   = xb + QKV_SZ;          // Wq,Wk,Wv bf16
        Wob   = Wb3 + 3 * W_SZ;       // Wo bf16
        qkv   = Wob + W_SZ;           // q,k,v bf16 head-major
        attnb = xb;                   // overlay x (dead after QKV gemm)
    } else {                          // proven 33.6 MB budget
        qkv   = ws16;
        attnb = qkv + 3 * QKV_SZ;
        Wb3   = attnb;                // overlay attn (dead before flash writes it)
        Wob   = qkv;                  // overlay q (dead after flash)
    }

    cvt_f32_bf16<<<512, 256, 0, stream>>>(Wq, Wb3,            131072);
    cvt_f32_bf16<<<512, 256, 0, stream>>>(Wk, Wb3 + W_SZ,     131072);
    cvt_f32_bf16<<<512, 256, 0, stream>>>(Wv, Wb3 + 2 * W_SZ, 131072);
    if (big) cvt_f32_bf16<<<2048, 256, 0, stream>>>(x, xb, 524288);

    const dim3 gqkv(8, 32, 3);
    if (big) gemm_bt<0, 1><<<gqkv, 256, 0, stream>>>(xb, Wb3, qkv, nullptr);
    else     gemm_bt<0, 0><<<gqkv, 256, 0, stream>>>(x,  Wb3, qkv, nullptr);

    flash_attn<<<dim3(16, 32), 256, 0, stream>>>(qkv, sb, sw, attnb);

    cvt_f32_bf16<<<512, 256, 0, stream>>>(Wo, Wob, 131072);
    gemm_bt<1, 1><<<dim3(8, 32, 1), 256, 0, stream>>>(attnb, Wob, (float*)d_out, bo);
}

// Round 4
// 256.436 us; speedup vs baseline: 1.8534x; 1.0685x over previous
//
#include <hip/hip_runtime.h>

// QuantFinanceAttention: B=2, T=2048, C=1024, H=16, dk=64. fp32 I/O, bf16 MFMA internals.
// cvt(all) | QKV gemm (rope fused) | flash (V^T staged, ones-MFMA rowsum, balanced grid) | proj.

typedef __bf16 bf16x8 __attribute__((ext_vector_type(8)));
typedef float f32x4 __attribute__((ext_vector_type(4)));
typedef unsigned short u16x8 __attribute__((ext_vector_type(8)));

__device__ __forceinline__ unsigned short f2bf(float f) {
    union { float f; unsigned int u; } c; c.f = f;
    unsigned int u = c.u;
    unsigned int r = u + 0x7fffu + ((u >> 16) & 1u);  // RNE
    return (unsigned short)(r >> 16);
}
__device__ __forceinline__ void stage8_f32(unsigned short* dst, const float* src) {
    const float4 a = *(const float4*)src;
    const float4 b = *(const float4*)(src + 4);
    u16x8 v;
    v[0] = f2bf(a.x); v[1] = f2bf(a.y); v[2] = f2bf(a.z); v[3] = f2bf(a.w);
    v[4] = f2bf(b.x); v[5] = f2bf(b.y); v[6] = f2bf(b.z); v[7] = f2bf(b.w);
    *(u16x8*)dst = v;
}
__device__ __forceinline__ void async16(const unsigned short* g, unsigned short* l) {
    __builtin_amdgcn_global_load_lds(
        (const __attribute__((address_space(1))) void*)g,
        (__attribute__((address_space(3))) void*)l, 16, 0, 0);
}

// Fused fp32->bf16 convert. dst layout: [x(524288 g8) if hasX][Wq][Wk][Wv][Wo] (131072 g8 each).
__global__ __launch_bounds__(256) void cvt_all(
    const float* __restrict__ x, const float* __restrict__ Wq, const float* __restrict__ Wk,
    const float* __restrict__ Wv, const float* __restrict__ Wo,
    unsigned short* __restrict__ dst, int hasX, int n8)
{
    const int i = blockIdx.x * 256 + threadIdx.x;
    if (i >= n8) return;
    int r = i;
    const float* src; int off;
    const int xg = hasX ? 524288 : 0;
    if (r < xg) { src = x; off = r; }
    else {
        r -= xg;
        const int w = r >> 17, o = r & 131071;
        src = (w == 0) ? Wq : (w == 1) ? Wk : (w == 2) ? Wv : Wo;
        off = o;
    }
    stage8_f32(&dst[(size_t)i * 8], &src[(size_t)off * 8]);
}

// C[m,n] = sum_k A[m,k]*W[n,k], K=1024. W bf16 (base + z*1M for MODE 0).
// MODE 0: out = qkv bf16 head-major [z][bh][t][d], rope fused for z<2. A bf16 if A_BF16 else fp32.
// MODE 1: out = fp32 [m][n] + bias[n]. A bf16.
template<int MODE, int A_BF16>
__global__ __launch_bounds__(256) void gemm_bt(
    const void* __restrict__ Av, const unsigned short* __restrict__ Wb,
    void* __restrict__ outv, const float* __restrict__ bias)
{
    constexpr int K = 1024, BK = 32;
    __shared__ __align__(16) unsigned short As[128 * BK];
    __shared__ __align__(16) unsigned short Bs[128 * BK];
    const int tid = threadIdx.x;
    const int wid = tid >> 6, lane = tid & 63, g = lane >> 4, l = lane & 15;
    const int wm = (wid & 1) * 64, wn = (wid >> 1) * 64;
    const int m0 = blockIdx.y * 128, n0 = blockIdx.x * 128;
    const int z = blockIdx.z;
    const unsigned short* W = Wb + (size_t)z * 1048576;

    f32x4 acc[4][4];
#pragma unroll
    for (int i = 0; i < 4; ++i)
#pragma unroll
        for (int j = 0; j < 4; ++j) acc[i][j] = f32x4{0.f, 0.f, 0.f, 0.f};

    const int r = tid >> 2;
    const int c = (tid & 3) * 8;
    unsigned short* AsW = &As[wid * 512];
    unsigned short* BsW = &Bs[wid * 512];

    for (int k0 = 0; k0 < K; k0 += BK) {
        __syncthreads();
        if (A_BF16) {
            const unsigned short* A = (const unsigned short*)Av;
            async16(&A[(size_t)(m0 + r) * K + k0 + c], AsW);
            async16(&A[(size_t)(m0 + 64 + r) * K + k0 + c], AsW + 2048);
        } else {
            const float* A = (const float*)Av;
            stage8_f32(&As[tid * 8],        &A[(size_t)(m0 + r) * K + k0 + c]);
            stage8_f32(&As[tid * 8 + 2048], &A[(size_t)(m0 + 64 + r) * K + k0 + c]);
        }
        async16(&W[(size_t)(n0 + r) * K + k0 + c], BsW);
        async16(&W[(size_t)(n0 + 64 + r) * K + k0 + c], BsW + 2048);
        __syncthreads();

        bf16x8 af[4], bfr[4];
#pragma unroll
        for (int im = 0; im < 4; ++im) af[im]  = *(const bf16x8*)&As[(wm + im * 16 + l) * BK + g * 8];
#pragma unroll
        for (int in = 0; in < 4; ++in) bfr[in] = *(const bf16x8*)&Bs[(wn + in * 16 + l) * BK + g * 8];
#pragma unroll
        for (int im = 0; im < 4; ++im)
#pragma unroll
            for (int in = 0; in < 4; ++in)
                acc[im][in] = __builtin_amdgcn_mfma_f32_16x16x32_bf16(af[im], bfr[in], acc[im][in], 0, 0, 0);
    }

    if (MODE == 1) {
#pragma unroll
        for (int im = 0; im < 4; ++im)
#pragma unroll
            for (int in = 0; in < 4; ++in) {
                const int n = n0 + wn + in * 16 + l;
#pragma unroll
                for (int i = 0; i < 4; ++i) {
                    const int m = m0 + wm + im * 16 + g * 4 + i;
                    ((float*)outv)[(size_t)m * 1024 + n] = acc[im][in][i] + bias[n];
                }
            }
    } else {
        unsigned short* outq = (unsigned short*)outv + (size_t)z * 4194304;
        if (z < 2) {
            float freq[2];
#pragma unroll
            for (int in = 0; in < 2; ++in)
                freq[in] = exp2f(-(float)(in * 16 + l) * 0.41524101186f);  // log2(10000)/32
#pragma unroll
            for (int im = 0; im < 4; ++im)
#pragma unroll
                for (int i = 0; i < 4; ++i) {
                    const int m = m0 + wm + im * 16 + g * 4 + i;
                    const int b = m >> 11, t = m & 2047;
#pragma unroll
                    for (int in = 0; in < 2; ++in) {
                        const int n = n0 + wn + in * 16 + l;
                        const int h = n >> 6, d = n & 63;
                        const float ang = (float)t * freq[in];
                        const float cs = __cosf(ang), sn = __sinf(ang);
                        const float x1 = acc[im][in][i], x2 = acc[im][in + 2][i];
                        const size_t bidx = (((size_t)b * 16 + h) * 2048 + t) << 6;
                        outq[bidx + d]      = f2bf(x1 * cs - x2 * sn);
                        outq[bidx + d + 32] = f2bf(x2 * cs + x1 * sn);
                    }
                }
        } else {
#pragma unroll
            for (int im = 0; im < 4; ++im)
#pragma unroll
                for (int in = 0; in < 4; ++in) {
                    const int n = n0 + wn + in * 16 + l;
                    const int h = n >> 6, d = n & 63;
#pragma unroll
                    for (int i = 0; i < 4; ++i) {
                        const int m = m0 + wm + im * 16 + g * 4 + i;
                        const int b = m >> 11, t = m & 2047;
                        outq[((((size_t)b * 16 + h) * 2048 + t) << 6) + d] = f2bf(acc[im][in][i]);
                    }
                }
        }
    }
}

// Flash attention. 1024 blocks (statically balanced qt assignment), 4 waves x 16 q-rows.
// V staged transposed; rowsum via ones-MFMA; max via 4 swizzle rounds.
__global__ __launch_bounds__(256) void flash_attn(
    const unsigned short* __restrict__ QKV, const float* __restrict__ sbias,
    const float* __restrict__ sw, unsigned short* __restrict__ attn)
{
    constexpr int T = 2048;
    __shared__ __align__(16) unsigned short Ks[64 * 72];
    __shared__ __align__(16) unsigned short VsT[64 * 72];   // [d][key]
    __shared__ __align__(16) unsigned short Ps[4][16 * 72];
    const int tid = threadIdx.x, wid = tid >> 6, lane = tid & 63, g = lane >> 4, l = lane & 15;
    // balanced mapping: the 4 blocks {c, c+256, c+512, c+768} get chunk counts summing to 66
    const int id = blockIdx.x;
    const int j = id >> 8, s = (id & 255) >> 5, bh = id & 31;
    const int qt = j * 8 + ((j & 1) ? (7 - s) : s);
    const int b = bh >> 4, h = bh & 15;

    const unsigned short* Q  = QKV;
    const unsigned short* Kg = QKV + 4194304;
    const unsigned short* Vg = QKV + 8388608;
    const size_t base = (size_t)bh * T * 64;
    const float bias = sbias[h];
    const float* swb = sw + b * T;

    bf16x8 onef;
#pragma unroll
    for (int q8 = 0; q8 < 8; ++q8) onef[q8] = (__bf16)1.0f;

    const int q0 = qt * 64;
    const int qrow = q0 + wid * 16 + l;
    const bf16x8 qf0 = *(const bf16x8*)&Q[base + (size_t)qrow * 64 + g * 8];
    const bf16x8 qf1 = *(const bf16x8*)&Q[base + (size_t)qrow * 64 + 32 + g * 8];

    float mrow[4] = {-1e30f, -1e30f, -1e30f, -1e30f};
    float lrow[4] = {0.f, 0.f, 0.f, 0.f};
    f32x4 oacc[4];
#pragma unroll
    for (int dt = 0; dt < 4; ++dt) oacc[dt] = f32x4{0.f, 0.f, 0.f, 0.f};

    for (int ch = 0; ch <= qt; ++ch) {
        const int k0 = ch * 64;
        __syncthreads();
        {   // K: 64x64 bf16, 2x16B per thread
            const int kr = tid >> 3, kc = (tid & 7) * 8;
            *(u16x8*)&Ks[kr * 72 + kc]        = *(const u16x8*)&Kg[base + (size_t)(k0 + kr) * 64 + kc];
            *(u16x8*)&Ks[(kr + 32) * 72 + kc] = *(const u16x8*)&Kg[base + (size_t)(k0 + 32 + kr) * 64 + kc];
        }
        {   // V transposed: thread loads keys (2r,2r+1) x 8 d, writes 8 packed b32 to VsT[d][key]
            const int vr = (tid & 31) * 2, vd = (tid >> 5) * 8;
            const u16x8 v0 = *(const u16x8*)&Vg[base + (size_t)(k0 + vr) * 64 + vd];
            const u16x8 v1 = *(const u16x8*)&Vg[base + (size_t)(k0 + vr + 1) * 64 + vd];
#pragma unroll
            for (int jj = 0; jj < 8; ++jj) {
                const unsigned int pack = (unsigned int)v0[jj] | ((unsigned int)v1[jj] << 16);
                *(unsigned int*)&VsT[(vd + jj) * 72 + vr] = pack;
            }
        }
        __syncthreads();

        const bool diag = (ch == qt);
        float sv[4][4];
#pragma unroll
        for (int sub = 0; sub < 4; ++sub) {
            const bf16x8 kf0 = *(const bf16x8*)&Ks[(sub * 16 + l) * 72 + g * 8];
            const bf16x8 kf1 = *(const bf16x8*)&Ks[(sub * 16 + l) * 72 + 32 + g * 8];
            f32x4 s4 = f32x4{0.f, 0.f, 0.f, 0.f};
            s4 = __builtin_amdgcn_mfma_f32_16x16x32_bf16(qf0, kf0, s4, 0, 0, 0);
            s4 = __builtin_amdgcn_mfma_f32_16x16x32_bf16(qf1, kf1, s4, 0, 0, 0);
            const int kc = k0 + sub * 16 + l;
            const float w = swb[kc];
            const float a = w * 0.125f, cst = w * bias;
#pragma unroll
            for (int i = 0; i < 4; ++i) {
                float x = s4[i] * a + cst;
                if (diag) {
                    const int qr = q0 + wid * 16 + g * 4 + i;
                    x = (kc <= qr) ? x : -1e30f;
                }
                sv[sub][i] = x;
            }
        }

        // running max + exp (sum comes later via ones-MFMA)
        float alpha[4];
#pragma unroll
        for (int i = 0; i < 4; ++i) {
            float mx = fmaxf(fmaxf(sv[0][i], sv[1][i]), fmaxf(sv[2][i], sv[3][i]));
#pragma unroll
            for (int off = 1; off < 16; off <<= 1) mx = fmaxf(mx, __shfl_xor(mx, off));
            const float mnew = fmaxf(mrow[i], mx);
            alpha[i] = __expf(mrow[i] - mnew);
            mrow[i] = mnew;
#pragma unroll
            for (int sub = 0; sub < 4; ++sub) sv[sub][i] = __expf(sv[sub][i] - mnew);
        }
#pragma unroll
        for (int dt = 0; dt < 4; ++dt)
#pragma unroll
            for (int i = 0; i < 4; ++i) oacc[dt][i] *= alpha[i];

        // P: C-layout -> LDS -> A-layout (per-wave buffer)
#pragma unroll
        for (int sub = 0; sub < 4; ++sub)
#pragma unroll
            for (int i = 0; i < 4; ++i)
                Ps[wid][(g * 4 + i) * 72 + sub * 16 + l] = f2bf(sv[sub][i]);
        __threadfence_block();
        bf16x8 pf[2];
        pf[0] = *(const bf16x8*)&Ps[wid][l * 72 + g * 8];
        pf[1] = *(const bf16x8*)&Ps[wid][l * 72 + 32 + g * 8];

        // row-sum of (bf16-rounded) P via ones-MFMA -> C-layout rows match lrow
        f32x4 ls = f32x4{0.f, 0.f, 0.f, 0.f};
        ls = __builtin_amdgcn_mfma_f32_16x16x32_bf16(pf[0], onef, ls, 0, 0, 0);
        ls = __builtin_amdgcn_mfma_f32_16x16x32_bf16(pf[1], onef, ls, 0, 0, 0);
#pragma unroll
        for (int i = 0; i < 4; ++i) lrow[i] = lrow[i] * alpha[i] + ls[i];

        // O += P V : B-fragment = vector read from VsT[d][key]
#pragma unroll
        for (int ks = 0; ks < 2; ++ks)
#pragma unroll
            for (int dt = 0; dt < 4; ++dt) {
                const bf16x8 vf = *(const bf16x8*)&VsT[(dt * 16 + l) * 72 + ks * 32 + g * 8];
                oacc[dt] = __builtin_amdgcn_mfma_f32_16x16x32_bf16(pf[ks], vf, oacc[dt], 0, 0, 0);
            }
    }

#pragma unroll
    for (int i = 0; i < 4; ++i) lrow[i] = 1.0f / lrow[i];
#pragma unroll
    for (int dt = 0; dt < 4; ++dt)
#pragma unroll
        for (int i = 0; i < 4; ++i) {
            const int qr = q0 + wid * 16 + g * 4 + i;
            attn[(size_t)(b * T + qr) * 1024 + h * 64 + dt * 16 + l] = f2bf(oacc[dt][i] * lrow[i]);
        }
}

extern "C" void kernel_launch(void* const* d_in, const int* in_sizes, int n_in,
                              void* d_out, int out_size, void* d_ws, size_t ws_size,
                              hipStream_t stream) {
    const float* x  = (const float*)d_in[0];
    const float* Wq = (const float*)d_in[1];
    const float* Wk = (const float*)d_in[2];
    const float* Wv = (const float*)d_in[3];
    const float* Wo = (const float*)d_in[4];
    const float* bo = (const float*)d_in[5];
    const float* sb = (const float*)d_in[6];
    const float* sw = (const float*)d_in[7];

    const size_t QKV_SZ = 4194304;   // shorts per q/k/v tensor
    const size_t W_SZ   = 1048576;   // shorts per weight matrix
    unsigned short* ws16 = (unsigned short*)d_ws;
    const bool big = ws_size >= 2 * (4 * QKV_SZ + 4 * W_SZ);  // 41.9 MB

    if (big) {
        unsigned short* xb    = ws16;            // x bf16
        unsigned short* Wb3   = xb + QKV_SZ;     // Wq,Wk,Wv
        unsigned short* Wob   = Wb3 + 3 * W_SZ;  // Wo
        unsigned short* qkv   = Wob + W_SZ;      // q,k,v head-major
        unsigned short* attnb = xb;              // overlay x (dead after QKV gemm)

        cvt_all<<<4096, 256, 0, stream>>>(x, Wq, Wk, Wv, Wo, xb, 1, 1048576);
        gemm_bt<0, 1><<<dim3(8, 32, 3), 256, 0, stream>>>(xb, Wb3, qkv, nullptr);
        flash_attn<<<1024, 256, 0, stream>>>(qkv, sb, sw, attnb);
        gemm_bt<1, 1><<<dim3(8, 32, 1), 256, 0, stream>>>(attnb, Wob, (float*)d_out, bo);
    } else {                                     // 33.6 MB fallback
        unsigned short* qkv   = ws16;
        unsigned short* attnb = qkv + 3 * QKV_SZ;
        unsigned short* Wb3   = attnb;           // overlay attn (dead until flash)
        unsigned short* Wob   = qkv;             // overlay q (dead after flash)

        cvt_all<<<1536, 256, 0, stream>>>(x, Wq, Wk, Wv, Wo, Wb3, 0, 393216);
        gemm_bt<0, 0><<<dim3(8, 32, 3), 256, 0, stream>>>(x, Wb3, qkv, nullptr);
        flash_attn<<<1024, 256, 0, stream>>>(qkv, sb, sw, attnb);
        cvt_all<<<512, 256, 0, stream>>>(x, Wo, Wo, Wo, Wo, Wob, 0, 131072);
        gemm_bt<1, 1><<<dim3(8, 32, 1), 256, 0, stream>>>(attnb, Wob, (float*)d_out, bo);
    }
}